// Round 1
// baseline (1884.692 us; speedup 1.0000x reference)
//
#include <hip/hip_runtime.h>
#include <math.h>

#define SELU_ALPHA 1.6732632423543772f
#define SELU_SCALE 1.0507009873554805f

__device__ __forceinline__ float selu_f(float x) {
    return x > 0.f ? SELU_SCALE * x : SELU_SCALE * SELU_ALPHA * (__expf(x) - 1.f);
}
__device__ __forceinline__ float sigmoid_f(float x) {
    return 1.f / (1.f + __expf(-x));
}

// Depthwise 3x3 (groups=128) on concat(x_t, h_{t-1}) + BN1 + SELU -> z1 (fp32)
// grid: (16 s-chunks, 128 cc, 8 b), block 256 (one pixel per thread)
__global__ __launch_bounds__(256) void dw_kernel(
    const float* __restrict__ x, const float* __restrict__ hprev /* = d_out */,
    const float* __restrict__ dw_w,
    const float* __restrict__ g1, const float* __restrict__ b1,
    const float* __restrict__ m1, const float* __restrict__ v1,
    float* __restrict__ z1, int t)
{
    int tid = threadIdx.x;
    int s = blockIdx.x * 256 + tid;
    int cc = blockIdx.y;
    int b = blockIdx.z;
    int yy = s >> 6, xx = s & 63;

    const float* src;
    bool zero_src = false;
    if (cc < 64) {
        // x[b][t][cc][.][.]
        src = x + (((size_t)(b * 20 + t) * 64 + cc) << 12);
    } else {
        if (t == 0) zero_src = true;        // h_0 = 0
        // h_{t-1} lives in d_out at [b][t-1][cc-64][.][.]
        src = hprev + (((size_t)(b * 20 + (t - 1)) * 64 + (cc - 64)) << 12);
    }

    float acc = 0.f;
    if (!zero_src) {
        #pragma unroll
        for (int ky = 0; ky < 3; ++ky) {
            int y2 = yy + ky - 1;
            if (y2 < 0 || y2 > 63) continue;
            #pragma unroll
            for (int kx = 0; kx < 3; ++kx) {
                int x2 = xx + kx - 1;
                if (x2 < 0 || x2 > 63) continue;
                acc += dw_w[cc * 9 + ky * 3 + kx] * src[(y2 << 6) + x2];
            }
        }
    }
    float scale = g1[cc] * rsqrtf(v1[cc] + 1e-5f);
    float z = (acc - m1[cc]) * scale + b1[cc];
    z1[(((size_t)b * 128 + cc) << 12) + s] = selu_f(z);
}

// Transpose pw_w [256][128] -> wT [128][256] once per launch (coalesced read)
__global__ __launch_bounds__(256) void wt_kernel(const float* __restrict__ pw_w,
                                                 float* __restrict__ wT)
{
    int i = blockIdx.x * 256 + threadIdx.x;   // i = c4*128 + cc
    int c4 = i >> 7, cc = i & 127;
    wT[cc * 256 + c4] = pw_w[i];
}

// Pointwise 1x1 conv (K=128 -> 256 gate channels) + BN2 + SELU + sigmoid +
// LSTM cell update, writing h into d_out and c into ws.
// grid: (16 s-chunks, 4 hc-tiles of 16, 8 b), block 256 (one s per thread)
__global__ __launch_bounds__(256) void pw_kernel(
    const float* __restrict__ z1, const float* __restrict__ wT,
    const float* __restrict__ g2, const float* __restrict__ b2,
    const float* __restrict__ m2, const float* __restrict__ v2,
    float* __restrict__ cbuf, float* __restrict__ out, int t)
{
    // wlds[cc][f] where f = gate*16 + j (j = hc within this block's 16)
    __shared__ float wlds[128 * 64];
    int tid = threadIdx.x;
    int hc0 = blockIdx.y * 16;
    int b = blockIdx.z;
    int s = blockIdx.x * 256 + tid;

    // Linear LDS fill (no bank conflicts); wT read is 16-float contiguous runs
    for (int i = tid; i < 128 * 64; i += 256) {
        int cc = i >> 6, f = i & 63;
        int g = f >> 4, j = f & 15;
        wlds[i] = wT[cc * 256 + g * 64 + hc0 + j];
    }
    __syncthreads();

    float acc[64];
    #pragma unroll
    for (int i = 0; i < 64; ++i) acc[i] = 0.f;

    const float* zp = z1 + (((size_t)b * 128) << 12) + s;
    for (int cc = 0; cc < 128; ++cc) {
        float v = zp[(size_t)cc << 12];
        const float4* w4 = (const float4*)(wlds + cc * 64);
        #pragma unroll
        for (int q = 0; q < 16; ++q) {
            float4 w = w4[q];                  // broadcast read: all lanes same addr
            acc[4 * q + 0] += v * w.x;
            acc[4 * q + 1] += v * w.y;
            acc[4 * q + 2] += v * w.z;
            acc[4 * q + 3] += v * w.w;
        }
    }

    // BN2 + SELU + sigmoid per gate output
    float gates[4][16];
    #pragma unroll
    for (int g = 0; g < 4; ++g) {
        #pragma unroll
        for (int j = 0; j < 16; ++j) {
            int c4 = g * 64 + hc0 + j;
            float scale = g2[c4] * rsqrtf(v2[c4] + 1e-5f);
            float z = (acc[g * 16 + j] - m2[c4]) * scale + b2[c4];
            gates[g][j] = sigmoid_f(selu_f(z));
        }
    }

    // LSTM update: i=gate0, f=gate1, o=gate2, g=gate3 (all sigmoided, per ref)
    #pragma unroll
    for (int j = 0; j < 16; ++j) {
        int hc = hc0 + j;
        size_t cidx = (((size_t)b * 64 + hc) << 12) + s;
        float cp = (t == 0) ? 0.f : cbuf[cidx];
        float cn = gates[1][j] * cp + gates[0][j] * gates[3][j];
        cbuf[cidx] = cn;
        out[(((size_t)(b * 20 + t) * 64 + hc) << 12) + s] = gates[2][j] * tanhf(cn);
    }
}

extern "C" void kernel_launch(void* const* d_in, const int* in_sizes, int n_in,
                              void* d_out, int out_size, void* d_ws, size_t ws_size,
                              hipStream_t stream) {
    const float* x    = (const float*)d_in[0];
    const float* dw_w = (const float*)d_in[1];
    const float* g1   = (const float*)d_in[2];
    const float* b1   = (const float*)d_in[3];
    const float* m1   = (const float*)d_in[4];
    const float* v1   = (const float*)d_in[5];
    const float* pw_w = (const float*)d_in[6];
    const float* g2   = (const float*)d_in[7];
    const float* b2   = (const float*)d_in[8];
    const float* m2   = (const float*)d_in[9];
    const float* v2   = (const float*)d_in[10];
    float* out = (float*)d_out;

    // ws layout: wT (32768 f) | cbuf (8*64*4096 f) | z1 (8*128*4096 f) = ~25.3 MB
    float* wT   = (float*)d_ws;
    float* cbuf = wT + 32768;
    float* z1   = cbuf + (size_t)8 * 64 * 4096;

    wt_kernel<<<128, 256, 0, stream>>>(pw_w, wT);

    for (int t = 0; t < 20; ++t) {
        dw_kernel<<<dim3(16, 128, 8), 256, 0, stream>>>(x, out, dw_w, g1, b1, m1, v1, z1, t);
        pw_kernel<<<dim3(16, 4, 8), 256, 0, stream>>>(z1, wT, g2, b2, m2, v2, cbuf, out, t);
    }
}

// Round 3
// 1136.414 us; speedup vs baseline: 1.6585x; 1.6585x over previous
//
#include <hip/hip_runtime.h>
#include <math.h>

typedef _Float16 half8 __attribute__((ext_vector_type(8)));
typedef float float4v __attribute__((ext_vector_type(4)));

#define SELU_ALPHA 1.6732632423543772f
#define SELU_SCALE 1.0507009873554805f

__device__ __forceinline__ float selu_f(float x) {
    return x > 0.f ? SELU_SCALE * x : SELU_SCALE * SELU_ALPHA * (__expf(x) - 1.f);
}
__device__ __forceinline__ float gate_f(float a, float sc, float sh) {
    // BN (pre-folded) -> SELU -> sigmoid
    float z = a * sc + sh;
    float s = selu_f(z);
    return 1.f / (1.f + __expf(-s));
}

// One-time prep: cast pw_w to f16 (layout [c4][cc] already MFMA-B friendly),
// fold BN1/BN2 into scale/shift pairs.
// NOTE: needs 32768 + 128 + 256 = 33152 threads -> 130 blocks of 256.
__global__ __launch_bounds__(256) void prep_kernel(
    const float* __restrict__ pw_w,
    const float* __restrict__ g1, const float* __restrict__ b1,
    const float* __restrict__ m1, const float* __restrict__ v1,
    const float* __restrict__ g2, const float* __restrict__ b2,
    const float* __restrict__ m2, const float* __restrict__ v2,
    _Float16* __restrict__ wB, float* __restrict__ bn1, float* __restrict__ bn2)
{
    int i = blockIdx.x * 256 + threadIdx.x;
    if (i < 32768) {
        wB[i] = (_Float16)pw_w[i];
    } else if (i < 32768 + 128) {
        int c = i - 32768;
        float sc = g1[c] * rsqrtf(v1[c] + 1e-5f);
        bn1[c] = sc;
        bn1[128 + c] = b1[c] - m1[c] * sc;
    } else if (i < 32768 + 128 + 256) {
        int c = i - 32896;
        float sc = g2[c] * rsqrtf(v2[c] + 1e-5f);
        bn2[c] = sc;
        bn2[256 + c] = b2[c] - m2[c] * sc;
    }
}

// Depthwise 3x3 + BN1 + SELU -> z1 (f16, layout [b][cc][s])
// grid: (16 s-chunks, 128 cc, 8 b), block 256 (one pixel per thread)
__global__ __launch_bounds__(256) void dw_kernel(
    const float* __restrict__ x, const float* __restrict__ hprev /* = d_out */,
    const float* __restrict__ dw_w, const float* __restrict__ bn1,
    _Float16* __restrict__ z1, int t)
{
    int tid = threadIdx.x;
    int s = blockIdx.x * 256 + tid;
    int cc = blockIdx.y;
    int b = blockIdx.z;
    int yy = s >> 6, xx = s & 63;

    const float* src;
    bool zero_src = false;
    if (cc < 64) {
        src = x + (((size_t)(b * 20 + t) * 64 + cc) << 12);
    } else if (t == 0) {
        zero_src = true;
        src = hprev;
    } else {
        src = hprev + (((size_t)(b * 20 + (t - 1)) * 64 + (cc - 64)) << 12);
    }

    float acc = 0.f;
    if (!zero_src) {
        #pragma unroll
        for (int ky = 0; ky < 3; ++ky) {
            int y2 = yy + ky - 1;
            if (y2 < 0 || y2 > 63) continue;
            #pragma unroll
            for (int kx = 0; kx < 3; ++kx) {
                int x2 = xx + kx - 1;
                if (x2 < 0 || x2 > 63) continue;
                acc += dw_w[cc * 9 + ky * 3 + kx] * src[(y2 << 6) + x2];
            }
        }
    }
    float z = acc * bn1[cc] + bn1[128 + cc];
    z1[(((size_t)b * 128 + cc) << 12) + s] = (_Float16)selu_f(z);
}

// Pointwise 1x1 conv as f16 MFMA GEMM (M=64 s-pixels per block, N=256 gates,
// K=128) + BN2 + SELU + sigmoid + LSTM update fused in epilogue.
// grid: (64 s-tiles, 8 b), block 256 = 4 waves.
// Wave w owns gate columns c4 = nt*64 + w*16 + (lane&15) for nt=0..3, so all
// four gates of one hc are in-lane for the LSTM update.
__global__ __launch_bounds__(256, 2) void pw_kernel(
    const _Float16* __restrict__ z1, const _Float16* __restrict__ wB,
    const float* __restrict__ bn2,
    float* __restrict__ cbuf, float* __restrict__ out, int t)
{
    // A tile: [64 s][128 cc] f16, pitch 136 halves (keeps 16B alignment,
    // breaks the 256B-stride bank pattern -> 2-way conflicts = free)
    __shared__ _Float16 Alds[64 * 136];

    int tid = threadIdx.x;
    int b = blockIdx.y;
    int s0 = blockIdx.x * 64;

    // ---- stage z1 tile: coalesced global f16 reads, u16 scatter into LDS ----
    {
        int cc = tid >> 1, hf = tid & 1;
        const half8* gp = (const half8*)(z1 + (((size_t)(b * 128 + cc)) << 12) + s0 + hf * 32);
        half8 v0 = gp[0], v1 = gp[1], v2 = gp[2], v3 = gp[3];
        int sl = hf * 32;
        #pragma unroll
        for (int j = 0; j < 8; ++j) Alds[(sl +      j) * 136 + cc] = v0[j];
        #pragma unroll
        for (int j = 0; j < 8; ++j) Alds[(sl +  8 + j) * 136 + cc] = v1[j];
        #pragma unroll
        for (int j = 0; j < 8; ++j) Alds[(sl + 16 + j) * 136 + cc] = v2[j];
        #pragma unroll
        for (int j = 0; j < 8; ++j) Alds[(sl + 24 + j) * 136 + cc] = v3[j];
    }

    int w = tid >> 6;
    int lane = tid & 63;
    int col = lane & 15, quad = lane >> 4;
    int hc = w * 16 + col;

    // ---- preload weight (B) fragments into registers: 16 x 16B per lane ----
    half8 bfr[4][4];   // [nt gate][kc]
    #pragma unroll
    for (int nt = 0; nt < 4; ++nt)
        #pragma unroll
        for (int kc = 0; kc < 4; ++kc)
            bfr[nt][kc] = *(const half8*)(wB + (size_t)((nt << 6) + hc) * 128 + kc * 32 + quad * 8);

    __syncthreads();

    // ---- MFMA main: 4 kc x (4 mt A-frags from LDS, 16 mfmas) ----
    float4v acc[4][4];
    #pragma unroll
    for (int mt = 0; mt < 4; ++mt)
        #pragma unroll
        for (int nt = 0; nt < 4; ++nt)
            acc[mt][nt] = (float4v){0.f, 0.f, 0.f, 0.f};

    #pragma unroll
    for (int kc = 0; kc < 4; ++kc) {
        half8 a[4];
        #pragma unroll
        for (int mt = 0; mt < 4; ++mt)
            a[mt] = *(const half8*)(Alds + (mt * 16 + col) * 136 + kc * 32 + quad * 8);
        #pragma unroll
        for (int mt = 0; mt < 4; ++mt)
            #pragma unroll
            for (int nt = 0; nt < 4; ++nt)
                acc[mt][nt] = __builtin_amdgcn_mfma_f32_16x16x32_f16(a[mt], bfr[nt][kc], acc[mt][nt], 0, 0, 0);
    }

    // ---- epilogue: BN2+SELU+sigmoid per gate, LSTM update ----
    float sc[4], sh[4];
    #pragma unroll
    for (int nt = 0; nt < 4; ++nt) {
        sc[nt] = bn2[(nt << 6) + hc];
        sh[nt] = bn2[256 + (nt << 6) + hc];
    }

    size_t cbase = (((size_t)(b * 64 + hc)) << 12) + s0;
    size_t obase = (((size_t)((b * 20 + t) * 64 + hc)) << 12) + s0;

    #pragma unroll
    for (int mt = 0; mt < 4; ++mt) {
        #pragma unroll
        for (int r = 0; r < 4; ++r) {
            int sl = mt * 16 + quad * 4 + r;
            float gi = gate_f(acc[mt][0][r], sc[0], sh[0]);
            float gf = gate_f(acc[mt][1][r], sc[1], sh[1]);
            float go = gate_f(acc[mt][2][r], sc[2], sh[2]);
            float gg = gate_f(acc[mt][3][r], sc[3], sh[3]);
            float cp = (t == 0) ? 0.f : cbuf[cbase + sl];
            float cn = gf * cp + gi * gg;
            cbuf[cbase + sl] = cn;
            // tanh via exp: tanh(x) = 1 - 2/(exp(2x)+1)
            float th = 1.f - 2.f / (__expf(2.f * cn) + 1.f);
            out[obase + sl] = go * th;
        }
    }
}

extern "C" void kernel_launch(void* const* d_in, const int* in_sizes, int n_in,
                              void* d_out, int out_size, void* d_ws, size_t ws_size,
                              hipStream_t stream) {
    const float* x    = (const float*)d_in[0];
    const float* dw_w = (const float*)d_in[1];
    const float* g1   = (const float*)d_in[2];
    const float* b1   = (const float*)d_in[3];
    const float* m1   = (const float*)d_in[4];
    const float* v1   = (const float*)d_in[5];
    const float* pw_w = (const float*)d_in[6];
    const float* g2   = (const float*)d_in[7];
    const float* b2   = (const float*)d_in[8];
    const float* m2   = (const float*)d_in[9];
    const float* v2   = (const float*)d_in[10];
    float* out = (float*)d_out;

    // ws layout (floats): wB16 [32768 halves = 16384 f] | bn1 [256 f] |
    //                     bn2 [512 f] | cbuf [8*64*4096 f] | z1 [8*128*4096 halves]
    _Float16* wB16 = (_Float16*)d_ws;
    float* bn1 = (float*)d_ws + 16384;
    float* bn2 = bn1 + 256;
    float* cbuf = bn2 + 512;
    _Float16* z1 = (_Float16*)(cbuf + (size_t)8 * 64 * 4096);

    prep_kernel<<<130, 256, 0, stream>>>(pw_w, g1, b1, m1, v1, g2, b2, m2, v2,
                                         wB16, bn1, bn2);

    for (int t = 0; t < 20; ++t) {
        dw_kernel<<<dim3(16, 128, 8), 256, 0, stream>>>(x, out, dw_w, bn1, z1, t);
        pw_kernel<<<dim3(64, 8), 256, 0, stream>>>(z1, wB16, bn2, cbuf, out, t);
    }
}